// Round 7
// baseline (2985.628 us; speedup 1.0000x reference)
//
#include <hip/hip_runtime.h>
#include <math.h>

#define ROWN 10000
#define COLN 4096
#define DIM 16
#define EN 1000000
#define RECLEN 160   // floats per column record (640 B = 40 float4)
// record float4 layout: [0]=(1,t,t^2/2,t^3/6) [1..4]=A diag [5..34]=B cross(120)
//                       [35..38]=h [39]=(g0, gamma_col, 0, 0)
#define NB 64        // sort chunks
#define CHUNK 15625  // EN / NB exact
#define PRE_BLKS 4096
#define PK_CAP 1261568   // >= EN + COLN*63 = 1,258,048; multiple of 64

struct Ctrl { int pk_len; int blkcnt; int pad[2]; unsigned long long acc; };

// compile-time (d,dp) pair table for the 120 cross terms
struct PairTab { int d[120]; int p[120]; };
__host__ __device__ constexpr PairTab make_tab() {
    PairTab t{};
    int i = 0;
    for (int d = 0; d < 15; ++d)
        for (int p = d + 1; p < 16; ++p) { t.d[i] = d; t.p[i] = p; ++i; }
    return t;
}
__constant__ constexpr PairTab TAB = make_tab();

// ---------- fused init: precompute_cols + chunk histogram ------
// gcur (counts) must be zeroed before this kernel.
__global__ __launch_bounds__(256) void init_fused(
    const float* __restrict__ z_cols, const float* __restrict__ gamma_cols,
    const float* __restrict__ L, const float* __restrict__ col_times,
    const int* __restrict__ col_idx_list, float* __restrict__ rec,
    const int* __restrict__ mc, int* __restrict__ gcnt)
{
    const int tid = threadIdx.x;
    if (blockIdx.x < PRE_BLKS) {
        __shared__ float Lsh[DIM][DIM];
        __shared__ float Gsh[DIM][DIM];
        __shared__ float zc[DIM];
        __shared__ float g1[DIM];
        const int c = blockIdx.x;
        const int cidx = col_idx_list[c];

        Lsh[tid >> 4][tid & 15] = L[(size_t)cidx * 256 + tid];
        if (tid < DIM) zc[tid] = z_cols[(size_t)c * DIM + tid];
        __syncthreads();

        const int d = tid >> 4, dp = tid & 15;
        float g = 0.0f;
        #pragma unroll
        for (int k = 0; k < DIM; ++k) g = fmaf(Lsh[d][k], Lsh[dp][k], g);
        Gsh[d][dp] = g;
        __syncthreads();

        if (tid < DIM) {
            float s = 0.0f;
            #pragma unroll
            for (int j = 0; j < DIM; ++j) s = fmaf(Gsh[tid][j], zc[j], s);
            g1[tid] = s;
        }
        __syncthreads();

        float* r = rec + (size_t)c * RECLEN;
        if (tid == 0) {
            float t = col_times[c];
            r[0] = 1.0f;
            r[1] = t;
            r[2] = 0.5f * t * t;
            r[3] = (t * t * t) * (1.0f / 6.0f);
            float g0 = 0.0f;
            #pragma unroll
            for (int j = 0; j < DIM; ++j) g0 = fmaf(g1[j], zc[j], g0);
            r[156] = g0;
            r[157] = gamma_cols[c];
            r[158] = 0.0f;
            r[159] = 0.0f;
        }
        if (tid < DIM) {
            r[4 + tid]   = Gsh[tid][tid];
            r[140 + tid] = 2.0f * g1[tid];
        }
        if (tid < 120) {
            r[20 + tid] = 2.0f * Gsh[TAB.d[tid]][TAB.p[tid]];
        }
    } else {
        // ----- per-chunk histogram, LDS-accumulated -----
        __shared__ int h[COLN];
        const int b = blockIdx.x - PRE_BLKS;
        for (int i = tid; i < COLN; i += 256) h[i] = 0;
        __syncthreads();
        const int lo = b * CHUNK, hi = min(lo + CHUNK, EN);
        for (int e = lo + tid; e < hi; e += 256)
            atomicAdd(&h[mc[e]], 1);
        __syncthreads();
        for (int i = tid; i < COLN; i += 256) {
            int v = h[i];
            if (v) atomicAdd(&gcnt[i], v);
        }
    }
}

// ---------- single-block scan: counts -> 64-aligned bucket bases ------------
__global__ __launch_bounds__(256) void scan_k(int* __restrict__ gc,
                                              Ctrl* __restrict__ ctrl)
{
    __shared__ int tot[COLN];
    __shared__ int sums[256];
    const int tid = threadIdx.x;
    #pragma unroll
    for (int i = 0; i < 16; ++i) {
        int c = i * 256 + tid;
        tot[c] = (gc[c] + 63) & ~63;          // pad each bucket to 64
    }
    __syncthreads();
    int s = 0;
    #pragma unroll
    for (int i = 0; i < 16; ++i) s += tot[tid * 16 + i];
    sums[tid] = s;
    __syncthreads();
    for (int off = 1; off < 256; off <<= 1) {
        int v = (tid >= off) ? sums[tid - off] : 0;
        __syncthreads();
        sums[tid] += v;
        __syncthreads();
    }
    int run = (tid == 0) ? 0 : sums[tid - 1];
    #pragma unroll
    for (int i = 0; i < 16; ++i) {
        int c = tid * 16 + i;
        int v = tot[c];
        gc[c] = run;          // padded exclusive base -> global cursor
        run += v;
    }
    if (tid == 255) ctrl->pk_len = run;       // total padded length
}

// ---------- scatter: per-block LDS hist -> reserve ranges -> place ----------
__global__ __launch_bounds__(512) void scatter_k(
    const int* __restrict__ mr, const int* __restrict__ mc,
    const int* __restrict__ yy, int* __restrict__ gcur,
    int* __restrict__ packed)
{
    __shared__ int lh[COLN];
    for (int i = threadIdx.x; i < COLN; i += 512) lh[i] = 0;
    __syncthreads();
    const int b = blockIdx.x;
    const int lo = b * CHUNK, hi = min(lo + CHUNK, EN);
    for (int e = lo + threadIdx.x; e < hi; e += 512)
        atomicAdd(&lh[mc[e]], 1);
    __syncthreads();
    for (int i = threadIdx.x; i < COLN; i += 512) {
        int cnt = lh[i];
        if (cnt) lh[i] = atomicAdd(&gcur[i], cnt);
    }
    __syncthreads();
    for (int e = lo + threadIdx.x; e < hi; e += 512) {
        int c = mc[e];
        int pos = atomicAdd(&lh[c], 1);            // LDS cursor
        packed[pos] = mr[e] | (yy[e] << 14) | (c << 17);  // 14+3+12 bits
    }
}

// log( Phi(hi) - Phi(lo) ), cancellation-free, branch-light, always finite.
__device__ __forceinline__ float log_cdf_diff_f(float hi, float lo) {
    const float r = 0.70710678118654752440f;
    if (hi + lo < 0.0f) { float t = hi; hi = -lo; lo = -t; }
    float d = erfcf(lo * r) - erfcf(hi * r);
    return logf(0.5f * fmaxf(d, 1e-37f));
}

__device__ __forceinline__ double atomicAddD(unsigned long long* p, double v) {
    unsigned long long old = *p, assumed;
    do {
        assumed = old;
        double cur = __longlong_as_double((long long)assumed);
        old = atomicCAS(p, assumed,
                        (unsigned long long)__double_as_longlong(cur + v));
    } while (old != assumed);
    return __longlong_as_double((long long)old);
}

// ---------- flat edge kernel; col is wave-uniform (64-aligned buckets) ------
__global__ __launch_bounds__(256) void edge_flat(
    const float* __restrict__ z_rows, const float* __restrict__ gamma_rows,
    const float4* __restrict__ rec4, const float* __restrict__ b,
    const float* __restrict__ sigma, const int* __restrict__ packed,
    Ctrl* __restrict__ ctrl, float* __restrict__ out)
{
    __shared__ float th[6];
    __shared__ double wave_sums[4];
    if (threadIdx.x == 0) { th[0] = -100000.0f; th[5] = 100000.0f; }
    if (threadIdx.x < 4)  th[1 + threadIdx.x] = b[threadIdx.x];
    const float inv_s = 1.0f / sigma[0];
    const int n = ctrl->pk_len;
    __syncthreads();

    double acc = 0.0;
    const int stride = gridDim.x * blockDim.x;
    for (int e = blockIdx.x * blockDim.x + threadIdx.x; e < n; e += stride) {
        const int p   = packed[e];
        // col is identical across the wave (buckets are 64-aligned/padded)
        const int col = __builtin_amdgcn_readfirstlane((int)(((unsigned)p) >> 17));
        const float4* __restrict__ rp = rec4 + (size_t)col * 40;  // uniform -> scalar
        const int yv  = (p >> 14) & 7;
        if (yv == 0) continue;                 // padding sentinel
        const int row = p & 0x3FFF;

        float4 t0 = rp[0];
        const float tp1 = t0.y, tp2 = t0.z, tp3 = t0.w;
        const float ga = gamma_rows[row];

        // z[d] = sum_v z_rows[v,row,d] * tp[v]; each v-slice is one 64B line
        float z[DIM];
        const float* zr = z_rows + (size_t)row * DIM;
        #pragma unroll
        for (int q = 0; q < 4; ++q) {
            float4 a0 = *(const float4*)(zr + 0 * (size_t)ROWN * DIM + q * 4);
            float4 a1 = *(const float4*)(zr + 1 * (size_t)ROWN * DIM + q * 4);
            float4 a2 = *(const float4*)(zr + 2 * (size_t)ROWN * DIM + q * 4);
            float4 a3 = *(const float4*)(zr + 3 * (size_t)ROWN * DIM + q * 4);
            z[4*q+0] = fmaf(a3.x, tp3, fmaf(a2.x, tp2, fmaf(a1.x, tp1, a0.x)));
            z[4*q+1] = fmaf(a3.y, tp3, fmaf(a2.y, tp2, fmaf(a1.y, tp1, a0.y)));
            z[4*q+2] = fmaf(a3.z, tp3, fmaf(a2.z, tp2, fmaf(a1.z, tp1, a0.z)));
            z[4*q+3] = fmaf(a3.w, tp3, fmaf(a2.w, tp2, fmaf(a1.w, tp1, a0.w)));
        }

        float qd = 0.0f;
        #pragma unroll
        for (int q = 0; q < 4; ++q) {
            float4 a = rp[1 + q];
            qd = fmaf(a.x, z[4*q+0] * z[4*q+0], qd);
            qd = fmaf(a.y, z[4*q+1] * z[4*q+1], qd);
            qd = fmaf(a.z, z[4*q+2] * z[4*q+2], qd);
            qd = fmaf(a.w, z[4*q+3] * z[4*q+3], qd);
        }
        float qc = 0.0f;
        #pragma unroll
        for (int q = 0; q < 30; ++q) {
            float4 bv = rp[5 + q];
            qc = fmaf(bv.x, z[TAB.d[4*q+0]] * z[TAB.p[4*q+0]], qc);
            qc = fmaf(bv.y, z[TAB.d[4*q+1]] * z[TAB.p[4*q+1]], qc);
            qc = fmaf(bv.z, z[TAB.d[4*q+2]] * z[TAB.p[4*q+2]], qc);
            qc = fmaf(bv.w, z[TAB.d[4*q+3]] * z[TAB.p[4*q+3]], qc);
        }
        float qh = 0.0f;
        #pragma unroll
        for (int q = 0; q < 4; ++q) {
            float4 hv = rp[35 + q];
            qh = fmaf(hv.x, z[4*q+0], qh);
            qh = fmaf(hv.y, z[4*q+1], qh);
            qh = fmaf(hv.z, z[4*q+2], qh);
            qh = fmaf(hv.w, z[4*q+3], qh);
        }

        float4 tail = rp[39];
        float qv = qd + qc - qh + tail.x;
        float dist = sqrtf(fmaxf(qv, 0.0f));
        float f = ga + tail.y - dist;

        acc += (double)log_cdf_diff_f((th[yv] - f) * inv_s,
                                      (th[yv - 1] - f) * inv_s);
    }

    #pragma unroll
    for (int off = 32; off > 0; off >>= 1) acc += __shfl_down(acc, off, 64);
    const int lane = threadIdx.x & 63;
    const int wid  = threadIdx.x >> 6;
    if (lane == 0) wave_sums[wid] = acc;
    __syncthreads();
    if (threadIdx.x == 0) {
        double t = wave_sums[0] + wave_sums[1] + wave_sums[2] + wave_sums[3];
        atomicAddD(&ctrl->acc, t);
        __threadfence();
        int done = atomicAdd(&ctrl->blkcnt, 1);
        if (done == (int)gridDim.x - 1) {
            __threadfence();
            double total = atomicAddD(&ctrl->acc, 0.0);
            out[0] = -(float)total;
        }
    }
}

extern "C" void kernel_launch(void* const* d_in, const int* in_sizes, int n_in,
                              void* d_out, int out_size, void* d_ws, size_t ws_size,
                              hipStream_t stream) {
    const float* z_rows       = (const float*)d_in[0];
    const float* z_cols       = (const float*)d_in[1];
    const float* gamma_rows   = (const float*)d_in[2];
    const float* gamma_cols   = (const float*)d_in[3];
    const float* L            = (const float*)d_in[4];
    const float* b            = (const float*)d_in[5];
    const float* sigma        = (const float*)d_in[6];
    const float* col_times    = (const float*)d_in[7];
    const int*   mat_rows     = (const int*)d_in[8];
    const int*   mat_cols     = (const int*)d_in[9];
    const int*   y            = (const int*)d_in[10];
    const int*   col_idx_list = (const int*)d_in[11];

    // workspace layout (all 16B-aligned)
    char* ws = (char*)d_ws;
    float* rec   = (float*)ws;                         // 2,621,440 B
    int*   gcur  = (int*)(ws + 2621440);               //    16,384 B
    Ctrl*  ctrl  = (Ctrl*)(ws + 2637824);              //       128 B
    int*   pk    = (int*)(ws + 2637952);               // PK_CAP*4 = 5,046,272 B

    hipMemsetAsync(gcur, 0, 16384 + 128, stream);            // counts + ctrl
    hipMemsetAsync(pk, 0, (size_t)PK_CAP * 4, stream);       // dummy sentinels
    init_fused<<<PRE_BLKS + NB, 256, 0, stream>>>(
        z_cols, gamma_cols, L, col_times, col_idx_list, rec, mat_cols, gcur);
    scan_k<<<1, 256, 0, stream>>>(gcur, ctrl);
    scatter_k<<<NB, 512, 0, stream>>>(mat_rows, mat_cols, y, gcur, pk);
    edge_flat<<<1024, 256, 0, stream>>>(z_rows, gamma_rows, (const float4*)rec,
                                        b, sigma, pk, ctrl, (float*)d_out);
}

// Round 8
// 202.258 us; speedup vs baseline: 14.7615x; 14.7615x over previous
//
#include <hip/hip_runtime.h>
#include <math.h>

#define ROWN 10000
#define COLN 4096
#define DIM 16
#define EN 1000000
#define RECLEN 160   // floats per column record (640 B = 40 float4)
// record float4 layout: [0]=(1,t,t^2/2,t^3/6) [1..4]=A diag [5..34]=B cross(120)
//                       [35..38]=h [39]=(g0, gamma_col, 0, 0)
#define NB 64        // sort chunks
#define CHUNK 15625  // EN / NB exact
#define PRE_BLKS 4096
#define PK_CAP 1261568   // >= EN + COLN*63 = 1,258,048; multiple of 64

struct Ctrl { int pk_len; int pad; double acc; };

// compile-time (d,dp) pair table for the 120 cross terms
struct PairTab { int d[120]; int p[120]; };
__host__ __device__ constexpr PairTab make_tab() {
    PairTab t{};
    int i = 0;
    for (int d = 0; d < 15; ++d)
        for (int p = d + 1; p < 16; ++p) { t.d[i] = d; t.p[i] = p; ++i; }
    return t;
}
__constant__ constexpr PairTab TAB = make_tab();

// ---------- fused init: precompute_cols + chunk histogram ------
// gcur (counts) must be zeroed before this kernel.
__global__ __launch_bounds__(256) void init_fused(
    const float* __restrict__ z_cols, const float* __restrict__ gamma_cols,
    const float* __restrict__ L, const float* __restrict__ col_times,
    const int* __restrict__ col_idx_list, float* __restrict__ rec,
    const int* __restrict__ mc, int* __restrict__ gcnt)
{
    const int tid = threadIdx.x;
    if (blockIdx.x < PRE_BLKS) {
        __shared__ float Lsh[DIM][DIM];
        __shared__ float Gsh[DIM][DIM];
        __shared__ float zc[DIM];
        __shared__ float g1[DIM];
        const int c = blockIdx.x;
        const int cidx = col_idx_list[c];

        Lsh[tid >> 4][tid & 15] = L[(size_t)cidx * 256 + tid];
        if (tid < DIM) zc[tid] = z_cols[(size_t)c * DIM + tid];
        __syncthreads();

        const int d = tid >> 4, dp = tid & 15;
        float g = 0.0f;
        #pragma unroll
        for (int k = 0; k < DIM; ++k) g = fmaf(Lsh[d][k], Lsh[dp][k], g);
        Gsh[d][dp] = g;
        __syncthreads();

        if (tid < DIM) {
            float s = 0.0f;
            #pragma unroll
            for (int j = 0; j < DIM; ++j) s = fmaf(Gsh[tid][j], zc[j], s);
            g1[tid] = s;
        }
        __syncthreads();

        float* r = rec + (size_t)c * RECLEN;
        if (tid == 0) {
            float t = col_times[c];
            r[0] = 1.0f;
            r[1] = t;
            r[2] = 0.5f * t * t;
            r[3] = (t * t * t) * (1.0f / 6.0f);
            float g0 = 0.0f;
            #pragma unroll
            for (int j = 0; j < DIM; ++j) g0 = fmaf(g1[j], zc[j], g0);
            r[156] = g0;
            r[157] = gamma_cols[c];
            r[158] = 0.0f;
            r[159] = 0.0f;
        }
        if (tid < DIM) {
            r[4 + tid]   = Gsh[tid][tid];
            r[140 + tid] = 2.0f * g1[tid];
        }
        if (tid < 120) {
            r[20 + tid] = 2.0f * Gsh[TAB.d[tid]][TAB.p[tid]];
        }
    } else {
        // ----- per-chunk histogram, LDS-accumulated -----
        __shared__ int h[COLN];
        const int b = blockIdx.x - PRE_BLKS;
        for (int i = tid; i < COLN; i += 256) h[i] = 0;
        __syncthreads();
        const int lo = b * CHUNK, hi = min(lo + CHUNK, EN);
        for (int e = lo + tid; e < hi; e += 256)
            atomicAdd(&h[mc[e]], 1);
        __syncthreads();
        for (int i = tid; i < COLN; i += 256) {
            int v = h[i];
            if (v) atomicAdd(&gcnt[i], v);
        }
    }
}

// ---------- single-block scan: counts -> 64-aligned bucket bases ------------
__global__ __launch_bounds__(256) void scan_k(int* __restrict__ gc,
                                              Ctrl* __restrict__ ctrl)
{
    __shared__ int tot[COLN];
    __shared__ int sums[256];
    const int tid = threadIdx.x;
    #pragma unroll
    for (int i = 0; i < 16; ++i) {
        int c = i * 256 + tid;
        tot[c] = (gc[c] + 63) & ~63;          // pad each bucket to 64
    }
    __syncthreads();
    int s = 0;
    #pragma unroll
    for (int i = 0; i < 16; ++i) s += tot[tid * 16 + i];
    sums[tid] = s;
    __syncthreads();
    for (int off = 1; off < 256; off <<= 1) {
        int v = (tid >= off) ? sums[tid - off] : 0;
        __syncthreads();
        sums[tid] += v;
        __syncthreads();
    }
    int run = (tid == 0) ? 0 : sums[tid - 1];
    #pragma unroll
    for (int i = 0; i < 16; ++i) {
        int c = tid * 16 + i;
        int v = tot[c];
        gc[c] = run;          // padded exclusive base -> global cursor
        run += v;
    }
    if (tid == 255) ctrl->pk_len = run;       // total padded length
}

// ---------- scatter: per-block LDS hist -> reserve ranges -> place ----------
__global__ __launch_bounds__(512) void scatter_k(
    const int* __restrict__ mr, const int* __restrict__ mc,
    const int* __restrict__ yy, int* __restrict__ gcur,
    int* __restrict__ packed)
{
    __shared__ int lh[COLN];
    for (int i = threadIdx.x; i < COLN; i += 512) lh[i] = 0;
    __syncthreads();
    const int b = blockIdx.x;
    const int lo = b * CHUNK, hi = min(lo + CHUNK, EN);
    for (int e = lo + threadIdx.x; e < hi; e += 512)
        atomicAdd(&lh[mc[e]], 1);
    __syncthreads();
    for (int i = threadIdx.x; i < COLN; i += 512) {
        int cnt = lh[i];
        if (cnt) lh[i] = atomicAdd(&gcur[i], cnt);
    }
    __syncthreads();
    for (int e = lo + threadIdx.x; e < hi; e += 512) {
        int c = mc[e];
        int pos = atomicAdd(&lh[c], 1);            // LDS cursor
        packed[pos] = mr[e] | (yy[e] << 14) | (c << 17);  // 14+3+12 bits
    }
}

// log( Phi(hi) - Phi(lo) ), cancellation-free, branch-light, always finite.
__device__ __forceinline__ float log_cdf_diff_f(float hi, float lo) {
    const float r = 0.70710678118654752440f;
    if (hi + lo < 0.0f) { float t = hi; hi = -lo; lo = -t; }
    float d = erfcf(lo * r) - erfcf(hi * r);
    return logf(0.5f * fmaxf(d, 1e-37f));
}

// ---------- flat edge kernel; col is wave-uniform (64-aligned buckets) ------
__global__ __launch_bounds__(256) void edge_flat(
    const float* __restrict__ z_rows, const float* __restrict__ gamma_rows,
    const float4* __restrict__ rec4, const float* __restrict__ b,
    const float* __restrict__ sigma, const int* __restrict__ packed,
    Ctrl* __restrict__ ctrl)
{
    __shared__ float th[6];
    __shared__ double wave_sums[4];
    if (threadIdx.x == 0) { th[0] = -100000.0f; th[5] = 100000.0f; }
    if (threadIdx.x < 4)  th[1 + threadIdx.x] = b[threadIdx.x];
    const float inv_s = 1.0f / sigma[0];
    const int n = ctrl->pk_len;
    __syncthreads();

    double acc = 0.0;
    const int stride = gridDim.x * blockDim.x;
    for (int e = blockIdx.x * blockDim.x + threadIdx.x; e < n; e += stride) {
        const int p   = packed[e];
        // col is identical across the wave (buckets are 64-aligned/padded)
        const int col = __builtin_amdgcn_readfirstlane((int)(((unsigned)p) >> 17));
        const float4* __restrict__ rp = rec4 + (size_t)col * 40;  // uniform -> scalar
        const int yv  = (p >> 14) & 7;
        if (yv == 0) continue;                 // padding sentinel
        const int row = p & 0x3FFF;

        float4 t0 = rp[0];
        const float tp1 = t0.y, tp2 = t0.z, tp3 = t0.w;
        const float ga = gamma_rows[row];

        // z[d] = sum_v z_rows[v,row,d] * tp[v]; each v-slice is one 64B line
        float z[DIM];
        const float* zr = z_rows + (size_t)row * DIM;
        #pragma unroll
        for (int q = 0; q < 4; ++q) {
            float4 a0 = *(const float4*)(zr + 0 * (size_t)ROWN * DIM + q * 4);
            float4 a1 = *(const float4*)(zr + 1 * (size_t)ROWN * DIM + q * 4);
            float4 a2 = *(const float4*)(zr + 2 * (size_t)ROWN * DIM + q * 4);
            float4 a3 = *(const float4*)(zr + 3 * (size_t)ROWN * DIM + q * 4);
            z[4*q+0] = fmaf(a3.x, tp3, fmaf(a2.x, tp2, fmaf(a1.x, tp1, a0.x)));
            z[4*q+1] = fmaf(a3.y, tp3, fmaf(a2.y, tp2, fmaf(a1.y, tp1, a0.y)));
            z[4*q+2] = fmaf(a3.z, tp3, fmaf(a2.z, tp2, fmaf(a1.z, tp1, a0.z)));
            z[4*q+3] = fmaf(a3.w, tp3, fmaf(a2.w, tp2, fmaf(a1.w, tp1, a0.w)));
        }

        float qd = 0.0f;
        #pragma unroll
        for (int q = 0; q < 4; ++q) {
            float4 a = rp[1 + q];
            qd = fmaf(a.x, z[4*q+0] * z[4*q+0], qd);
            qd = fmaf(a.y, z[4*q+1] * z[4*q+1], qd);
            qd = fmaf(a.z, z[4*q+2] * z[4*q+2], qd);
            qd = fmaf(a.w, z[4*q+3] * z[4*q+3], qd);
        }
        float qc = 0.0f;
        #pragma unroll
        for (int q = 0; q < 30; ++q) {
            float4 bv = rp[5 + q];
            qc = fmaf(bv.x, z[TAB.d[4*q+0]] * z[TAB.p[4*q+0]], qc);
            qc = fmaf(bv.y, z[TAB.d[4*q+1]] * z[TAB.p[4*q+1]], qc);
            qc = fmaf(bv.z, z[TAB.d[4*q+2]] * z[TAB.p[4*q+2]], qc);
            qc = fmaf(bv.w, z[TAB.d[4*q+3]] * z[TAB.p[4*q+3]], qc);
        }
        float qh = 0.0f;
        #pragma unroll
        for (int q = 0; q < 4; ++q) {
            float4 hv = rp[35 + q];
            qh = fmaf(hv.x, z[4*q+0], qh);
            qh = fmaf(hv.y, z[4*q+1], qh);
            qh = fmaf(hv.z, z[4*q+2], qh);
            qh = fmaf(hv.w, z[4*q+3], qh);
        }

        float4 tail = rp[39];
        float qv = qd + qc - qh + tail.x;
        float dist = sqrtf(fmaxf(qv, 0.0f));
        float f = ga + tail.y - dist;

        acc += (double)log_cdf_diff_f((th[yv] - f) * inv_s,
                                      (th[yv - 1] - f) * inv_s);
    }

    #pragma unroll
    for (int off = 32; off > 0; off >>= 1) acc += __shfl_down(acc, off, 64);
    const int lane = threadIdx.x & 63;
    const int wid  = threadIdx.x >> 6;
    if (lane == 0) wave_sums[wid] = acc;
    __syncthreads();
    if (threadIdx.x == 0) {
        double t = wave_sums[0] + wave_sums[1] + wave_sums[2] + wave_sums[3];
        atomicAdd(&ctrl->acc, t);        // native f64 atomic (NOT a CAS loop --
                                         // R7's CAS retry storm cost 2.8 ms)
    }
}

__global__ void finalize(const Ctrl* __restrict__ ctrl, float* __restrict__ out) {
    out[0] = -(float)ctrl->acc;
}

extern "C" void kernel_launch(void* const* d_in, const int* in_sizes, int n_in,
                              void* d_out, int out_size, void* d_ws, size_t ws_size,
                              hipStream_t stream) {
    const float* z_rows       = (const float*)d_in[0];
    const float* z_cols       = (const float*)d_in[1];
    const float* gamma_rows   = (const float*)d_in[2];
    const float* gamma_cols   = (const float*)d_in[3];
    const float* L            = (const float*)d_in[4];
    const float* b            = (const float*)d_in[5];
    const float* sigma        = (const float*)d_in[6];
    const float* col_times    = (const float*)d_in[7];
    const int*   mat_rows     = (const int*)d_in[8];
    const int*   mat_cols     = (const int*)d_in[9];
    const int*   y            = (const int*)d_in[10];
    const int*   col_idx_list = (const int*)d_in[11];

    // workspace layout (all 16B-aligned)
    char* ws = (char*)d_ws;
    float* rec   = (float*)ws;                         // 2,621,440 B
    int*   gcur  = (int*)(ws + 2621440);               //    16,384 B
    Ctrl*  ctrl  = (Ctrl*)(ws + 2637824);              //       128 B
    int*   pk    = (int*)(ws + 2637952);               // PK_CAP*4 = 5,046,272 B

    hipMemsetAsync(gcur, 0, 16384 + 128, stream);            // counts + ctrl
    hipMemsetAsync(pk, 0, (size_t)PK_CAP * 4, stream);       // dummy sentinels
    init_fused<<<PRE_BLKS + NB, 256, 0, stream>>>(
        z_cols, gamma_cols, L, col_times, col_idx_list, rec, mat_cols, gcur);
    scan_k<<<1, 256, 0, stream>>>(gcur, ctrl);
    scatter_k<<<NB, 512, 0, stream>>>(mat_rows, mat_cols, y, gcur, pk);
    edge_flat<<<2048, 256, 0, stream>>>(z_rows, gamma_rows, (const float4*)rec,
                                        b, sigma, pk, ctrl);
    finalize<<<1, 1, 0, stream>>>(ctrl, (float*)d_out);
}